// Round 1
// baseline (15261.887 us; speedup 1.0000x reference)
//
#include <hip/hip_runtime.h>

// TimeframeEncoder: 2-layer GRU-ish recurrence (SEQ=512) + final LayerNorm.
// Strategy R1: 16 blocks x 16 batch rows, recurrence fully inside one block
// (batch rows are independent -> zero grid syncs). bf16 MFMA 16x16x32 with
// weights pre-packed into B-fragment layout in d_ws; fp32 state in registers.

#define HID 256
#define SEQL 512
#define IDIM 64

typedef __bf16 bf16x8 __attribute__((ext_vector_type(8)));
typedef float f32x4 __attribute__((ext_vector_type(4)));

__device__ __forceinline__ unsigned short f2bf(float f) {
  unsigned int u = __builtin_bit_cast(unsigned int, f);
  u += 0x7fffu + ((u >> 16) & 1u);   // RNE; inputs are sanitized/finite
  return (unsigned short)(u >> 16);
}

__device__ __forceinline__ float sigm(float x) { return 1.0f / (1.0f + __expf(-x)); }
// tanh via exp, safe at +/-inf: 1 - 2/(e^{2x}+1)
__device__ __forceinline__ float tanh_(float x) { return 1.0f - 2.0f / (__expf(2.0f * x) + 1.0f); }

// ---------------------------------------------------------------------------
// Weight prep: convert used fp32 weight columns to bf16 B-fragments in ws.
// B-frag for mfma_f32_16x16x32_bf16: lane L holds B[k = (L>>4)*8 + j][n = L&15],
// j in [0,8). Tile (nt,kt) stored as 512 ushort: [lane][j].
// ws element layout (ushort):
//   Wz0p: tiles (nt<32, kt<10) at (nt*10+kt)*512          size 163840
//   Wc0p: base 163840, (nt<16, kt<10)                     size  81920
//   Wz1p: base 245760, (nt<32, kt<16)                     size 262144
//   Wc1p: base 507904, (nt<16, kt<16)                     size 131072
// total 638976 ushort = 1.22 MB
// ---------------------------------------------------------------------------
__global__ __launch_bounds__(256) void prep_weights(
    const float* __restrict__ Wz0, const float* __restrict__ Wc0,
    const float* __restrict__ Wz1, const float* __restrict__ Wc1,
    unsigned short* __restrict__ ws) {
  int idx = blockIdx.x * 256 + threadIdx.x;  // exactly 638976 threads
  const float* W;
  int stride, KT, base;
  if (idx < 163840)      { W = Wz0; stride = 768; KT = 10; base = 0; }
  else if (idx < 245760) { W = Wc0; stride = 256; KT = 10; base = 163840; idx -= 163840; }
  else if (idx < 507904) { W = Wz1; stride = 768; KT = 16; base = 245760; idx -= 245760; }
  else                   { W = Wc1; stride = 256; KT = 16; base = 507904; idx -= 507904; }
  int tile = idx >> 9;
  int t = idx & 511;
  int nt = tile / KT;
  int kt = tile - nt * KT;
  int n15 = t & 15;          // 16 consecutive tids -> 64B coalesced source read
  int klocal = t >> 4;       // 0..31
  int k = (kt << 5) + klocal;
  int n = (nt << 4) + n15;
  int lane = ((klocal >> 3) << 4) | n15;
  int j = klocal & 7;
  float v = W[k * stride + n];
  ws[base + (tile << 9) + (lane << 3) + j] = f2bf(v);
}

// ---------------------------------------------------------------------------
// Main recurrent kernel. Grid = 16 blocks (16 rows each), 1024 thr = 16 waves.
// Wave w owns output columns [16w, 16w+16) of z/htilde/h AND r-columns
// [256+16w, ...), so z and r*h pair with this thread's own fp32 h registers.
// LDS only holds bf16 A-operand fragment buffers + biases (58 KB).
// ---------------------------------------------------------------------------
__global__ __launch_bounds__(1024) void gru_main(
    const float* __restrict__ x,
    const float* __restrict__ bz0, const float* __restrict__ bc0,
    const float* __restrict__ bz1, const float* __restrict__ bc1,
    const float* __restrict__ gamma, const float* __restrict__ beta,
    const unsigned short* __restrict__ wsw,
    float* __restrict__ out) {
  __shared__ __align__(16) unsigned char lds[59392];
  unsigned short* A0  = (unsigned short*)lds;   // combined0 [h0 | x]  frags, 10 kt
  unsigned short* A0r = A0 + 5120;              // reset0   [r*h0 | x] frags
  unsigned short* A1  = A0 + 10240;             // combined1 [h1 | h0] frags, 16 kt
  unsigned short* A1r = A0 + 18432;             // reset1   [r1*h1 | h0]
  float* sb = (float*)(lds + 53248);            // biases: bz0[512] bc0[256] bz1[512] bc1[256]

  const int tid  = threadIdx.x;
  const int wave = tid >> 6;
  const int lane = tid & 63;
  const int l15  = lane & 15;
  const int quad = lane >> 4;
  const int row0 = blockIdx.x << 4;

  for (int i = tid; i < 1536; i += 1024) {
    float v;
    if (i < 512) v = bz0[i];
    else if (i < 768) v = bc0[i - 512];
    else if (i < 1280) v = bz1[i - 768];
    else v = bc1[i - 1280];
    sb[i] = v;
  }
  for (int i = tid; i < 26624; i += 1024) A0[i] = 0;  // zero all frag buffers (h parts)

  f32x4 h0 = {0.f, 0.f, 0.f, 0.f};
  f32x4 h1 = {0.f, 0.f, 0.f, 0.f};

  // this thread's owned (m = quad*4+i, k = colz) frag element indices
  const int colz = (wave << 4) | l15;
  const int dlo = ((colz >> 5) << 9) + ((((colz >> 3) & 3) << 4) + (quad << 2)) * 8 + (colz & 7);
  const int dhi = dlo + 4096;  // same element, k += 256 (8 kt tiles further)

  __syncthreads();

  const float bz0z = sb[colz],        bz0r = sb[256 + colz];
  const float bc0c = sb[512 + colz];
  const float bz1z = sb[768 + colz],  bz1r = sb[1024 + colz];
  const float bc1c = sb[1280 + colz];

  const bf16x8* __restrict__ wsv = (const bf16x8*)wsw;
  const int t2a = (wave * 10) * 64 + lane;             // Wz0p z-tile (nt=w)
  const int t2b = ((wave + 16) * 10) * 64 + lane;      // Wz0p r-tile (nt=w+16)
  const int t3  = (320 + wave * 10) * 64 + lane;       // Wc0p
  const int t4a = (480 + wave * 16) * 64 + lane;       // Wz1p z
  const int t4b = (480 + (wave + 16) * 16) * 64 + lane;// Wz1p r
  const int t5  = (992 + wave * 16) * 64 + lane;       // Wc1p

  // x staging: thread (wave=m, lane=c) loads x[row0+m][t][c] -> frag k=256+c
  const float* xp = x + (size_t)(row0 + wave) * (SEQL * IDIM) + lane;
  const int xdst = ((8 + (lane >> 5)) << 9) + ((((lane >> 3) & 3) << 4) + wave) * 8 + (lane & 7);

  for (int t = 0; t < SEQL; ++t) {
    // P1: x_t -> A0/A0r x-part (sanitize NaN->0, Inf->+/-10)
    float xv = xp[t * IDIM];
    if (!(xv == xv)) xv = 0.f;
    else if (isinf(xv)) xv = (xv > 0.f) ? 10.f : -10.f;
    unsigned short xb = f2bf(xv);
    A0[xdst] = xb;
    A0r[xdst] = xb;
    __syncthreads();

    // P2: gates0 = [h0|x] @ Wz0[:, :512] + bz0 ; z kept in regs, r*h0 -> A0r
    f32x4 az = {bz0z, bz0z, bz0z, bz0z};
    f32x4 ar = {bz0r, bz0r, bz0r, bz0r};
#pragma unroll
    for (int kt = 0; kt < 10; ++kt) {
      bf16x8 a  = *(const bf16x8*)(A0 + (kt << 9) + (lane << 3));
      bf16x8 b0 = wsv[t2a + (kt << 6)];
      bf16x8 b1 = wsv[t2b + (kt << 6)];
      az = __builtin_amdgcn_mfma_f32_16x16x32_bf16(a, b0, az, 0, 0, 0);
      ar = __builtin_amdgcn_mfma_f32_16x16x32_bf16(a, b1, ar, 0, 0, 0);
    }
    float z0r[4];
#pragma unroll
    for (int i = 0; i < 4; ++i) {
      z0r[i] = sigm(az[i]);
      float r = sigm(ar[i]);
      A0r[dlo + i * 8] = f2bf(r * h0[i]);
    }
    __syncthreads();

    // P3: htilde0 = tanh([r*h0|x] @ Wc0 + bc0); h0 = h0 + z*(ht-h0)
    f32x4 ac = {bc0c, bc0c, bc0c, bc0c};
#pragma unroll
    for (int kt = 0; kt < 10; ++kt) {
      bf16x8 a  = *(const bf16x8*)(A0r + (kt << 9) + (lane << 3));
      bf16x8 b0 = wsv[t3 + (kt << 6)];
      ac = __builtin_amdgcn_mfma_f32_16x16x32_bf16(a, b0, ac, 0, 0, 0);
    }
#pragma unroll
    for (int i = 0; i < 4; ++i) {
      float ht = tanh_(ac[i]);
      float hn = h0[i] + z0r[i] * (ht - h0[i]);
      h0[i] = hn;
      unsigned short hb = f2bf(hn);
      A0[dlo + i * 8]  = hb;  // next step's combined0 h-part
      A1[dhi + i * 8]  = hb;  // combined1 k = 256+colz (h0 part)
      A1r[dhi + i * 8] = hb;  // reset1 h0 part
    }
    __syncthreads();

    // P4: gates1 = [h1|h0] @ Wz1[:, :512] + bz1
    f32x4 az1 = {bz1z, bz1z, bz1z, bz1z};
    f32x4 ar1 = {bz1r, bz1r, bz1r, bz1r};
#pragma unroll
    for (int kt = 0; kt < 16; ++kt) {
      bf16x8 a  = *(const bf16x8*)(A1 + (kt << 9) + (lane << 3));
      bf16x8 b0 = wsv[t4a + (kt << 6)];
      bf16x8 b1 = wsv[t4b + (kt << 6)];
      az1 = __builtin_amdgcn_mfma_f32_16x16x32_bf16(a, b0, az1, 0, 0, 0);
      ar1 = __builtin_amdgcn_mfma_f32_16x16x32_bf16(a, b1, ar1, 0, 0, 0);
    }
    float z1r[4];
#pragma unroll
    for (int i = 0; i < 4; ++i) {
      z1r[i] = sigm(az1[i]);
      float r = sigm(ar1[i]);
      A1r[dlo + i * 8] = f2bf(r * h1[i]);
    }
    __syncthreads();

    // P5: htilde1; h1 update
    f32x4 ac1 = {bc1c, bc1c, bc1c, bc1c};
#pragma unroll
    for (int kt = 0; kt < 16; ++kt) {
      bf16x8 a  = *(const bf16x8*)(A1r + (kt << 9) + (lane << 3));
      bf16x8 b0 = wsv[t5 + (kt << 6)];
      ac1 = __builtin_amdgcn_mfma_f32_16x16x32_bf16(a, b0, ac1, 0, 0, 0);
    }
#pragma unroll
    for (int i = 0; i < 4; ++i) {
      float ht = tanh_(ac1[i]);
      h1[i] = h1[i] + z1r[i] * (ht - h1[i]);
      A1[dlo + i * 8] = f2bf(h1[i]);  // next step's combined1 h1-part
    }
    __syncthreads();
  }

  // Epilogue: LayerNorm(h1) per row. Stage fp32 h1 in LDS (reuse A0/A0r region).
  float* h1buf = (float*)lds;
#pragma unroll
  for (int i = 0; i < 4; ++i) h1buf[((quad << 2) + i) * 256 + colz] = h1[i];
  __syncthreads();

  float v[4], s = 0.f, sq = 0.f;
#pragma unroll
  for (int j = 0; j < 4; ++j) {
    v[j] = h1buf[wave * 256 + lane + (j << 6)];
    s += v[j];
    sq += v[j] * v[j];
  }
#pragma unroll
  for (int off = 32; off > 0; off >>= 1) {
    s  += __shfl_xor(s, off);
    sq += __shfl_xor(sq, off);
  }
  float mean = s * (1.f / 256.f);
  float var  = sq * (1.f / 256.f) - mean * mean;   // population var (jnp.var)
  float rstd = rsqrtf(var + 1e-5f);
  float* op = out + (size_t)(row0 + wave) * 256;
#pragma unroll
  for (int j = 0; j < 4; ++j) {
    int c = lane + (j << 6);
    op[c] = (v[j] - mean) * rstd * gamma[c] + beta[c];
  }
}

extern "C" void kernel_launch(void* const* d_in, const int* in_sizes, int n_in,
                              void* d_out, int out_size, void* d_ws, size_t ws_size,
                              hipStream_t stream) {
  const float* x     = (const float*)d_in[0];
  const float* Wz0   = (const float*)d_in[1];
  const float* bz0   = (const float*)d_in[2];
  const float* Wc0   = (const float*)d_in[3];
  const float* bc0   = (const float*)d_in[4];
  const float* Wz1   = (const float*)d_in[5];
  const float* bz1   = (const float*)d_in[6];
  const float* Wc1   = (const float*)d_in[7];
  const float* bc1   = (const float*)d_in[8];
  const float* gamma = (const float*)d_in[9];
  const float* beta  = (const float*)d_in[10];
  unsigned short* ws = (unsigned short*)d_ws;
  float* out = (float*)d_out;

  // 638976 weight elements -> bf16 B-fragment layout (re-run every launch; ws is re-poisoned)
  hipLaunchKernelGGL(prep_weights, dim3(2496), dim3(256), 0, stream, Wz0, Wc0, Wz1, Wc1, ws);
  // 16 blocks x 16 rows; whole recurrence in one launch, no grid sync needed
  hipLaunchKernelGGL(gru_main, dim3(16), dim3(1024), 0, stream,
                     x, bz0, bc0, bz1, bc1, gamma, beta, ws, out);
}